// Round 27
// baseline (95.617 us; speedup 1.0000x reference)
//
#include <hip/hip_runtime.h>
#include <hip/hip_bf16.h>
#include <math.h>

typedef unsigned short u16;
typedef __bf16 bf16x8 __attribute__((ext_vector_type(8)));
typedef short s16x4 __attribute__((ext_vector_type(4)));
typedef float f32x4 __attribute__((ext_vector_type(4)));
typedef u16 u16x8 __attribute__((ext_vector_type(8)));
typedef u16 u16x4 __attribute__((ext_vector_type(4)));

#define DM 1024
#define NH 16
#define SL 2048
#define BB 2
#define TOK (BB * SL)   // 4096 tokens

__device__ __forceinline__ u16 f2bf(float f) {
  union { float f; unsigned u; } v; v.f = f;
  unsigned r = v.u + 0x7FFFu + ((v.u >> 16) & 1u);
  return (u16)(r >> 16);
}

__device__ __forceinline__ float fexp2(float x) {
  float r; asm("v_exp_f32 %0, %1" : "=v"(r) : "v"(x)); return r;
}

__device__ __forceinline__ unsigned cvtpk(float lo, float hi) {
  unsigned r;
  asm("v_cvt_pk_bf16_f32 %0, %1, %2" : "=v"(r) : "v"(lo), "v"(hi));
  return r;
}

__device__ __forceinline__ float max3f(float a, float b, float c) {
  return fmaxf(fmaxf(a, b), c);   // clang fuses to v_max3_f32
}

// K=16 MFMA: A frag s16x4 = A[row=lane&15][k=(lane>>4)*4 + 0..3].
__device__ __forceinline__ f32x4 pv_mfma(s16x4 a, s16x4 b, f32x4 c) {
#if __has_builtin(__builtin_amdgcn_mfma_f32_16x16x16bf16_1k)
  return __builtin_amdgcn_mfma_f32_16x16x16bf16_1k(a, b, c, 0, 0, 0);
#else
  asm("v_mfma_f32_16x16x16_bf16 %0, %1, %2, %0" : "+v"(c) : "v"(a), "v"(b));
  return c;
#endif
}

typedef __attribute__((address_space(1))) const unsigned GU;
typedef __attribute__((address_space(3))) unsigned LU;
#define GLOAD16(g, l) __builtin_amdgcn_global_load_lds((GU*)(g), (LU*)(l), 16, 0, 0)

// BK=32 chunk swizzle: rows stride 64B, so rows r and r+4 share a bank group;
// XOR must span 16 rows. s(row) = (row&3) ^ ((row>>2)&3) (bijective per row).
__device__ __forceinline__ int swz4(int row) {
  return (row & 3) ^ ((row >> 2) & 3);
}

// ---------------- prep: 4x weight transpose-cast + x cast, one launch ------
__global__ __launch_bounds__(256) void prep(
    const float* __restrict__ x,
    const float* __restrict__ w0, const float* __restrict__ w1,
    const float* __restrict__ w2, const float* __restrict__ w3,
    u16* __restrict__ Xb, u16* __restrict__ Wall) {
  __shared__ u16 T[64][72];
  int bid = blockIdx.x;
  int tid = threadIdx.x;
  if (bid < 1024) {            // transpose: mat = bid>>8, 16x16 tiles of 64
    int mat = bid >> 8;
    const float* in = (mat == 0) ? w0 : (mat == 1) ? w1 : (mat == 2) ? w2 : w3;
    u16* o = Wall + ((size_t)mat << 20);
    int t2 = bid & 255;
    int k0 = (t2 & 15) * 64, n0 = (t2 >> 4) * 64;
    int r = tid >> 2;
    int c0 = (tid & 3) * 16;
#pragma unroll
    for (int j = 0; j < 16; j += 4) {
      float4 f = *(const float4*)(in + (size_t)(k0 + r) * 1024 + n0 + c0 + j);
      T[c0 + j + 0][r] = f2bf(f.x);
      T[c0 + j + 1][r] = f2bf(f.y);
      T[c0 + j + 2][r] = f2bf(f.z);
      T[c0 + j + 3][r] = f2bf(f.w);
    }
    __syncthreads();
    int n = tid >> 2, k1 = (tid & 3) * 16;
#pragma unroll
    for (int j = 0; j < 16; j += 8)
      *(u16x8*)(o + (size_t)(n0 + n) * 1024 + k0 + k1 + j) = *(const u16x8*)&T[n][k1 + j];
  } else {                     // cast x -> bf16 (2048 blocks x 256 x 8)
    int i = ((bid - 1024) * 256 + tid) * 8;
    float4 a = *(const float4*)(x + i);
    float4 b = *(const float4*)(x + i + 4);
    u16x8 o;
    o[0]=f2bf(a.x); o[1]=f2bf(a.y); o[2]=f2bf(a.z); o[3]=f2bf(a.w);
    o[4]=f2bf(b.x); o[5]=f2bf(b.y); o[6]=f2bf(b.z); o[7]=f2bf(b.w);
    *(u16x8*)(Xb + i) = o;
  }
}

// ---------------- GEMM: 3-buffer ring, BK=32, BM templated ----------------
// Loads per stage = BM/64 (A) + 2 (B). Counted-vmcnt steady-state wait must
// equal loads-per-stage: BM=128 -> vmcnt(4); BM=64 -> vmcnt(3).
// swz4 on BOTH stage-source and fragment-read (involution pair, R26 fix:
// ch^(row&3) left rows {0,4,8,12} 4-way bank-conflicting -> 3.1e6 counts).
template<int MODE, int BM>
__global__ __launch_bounds__(256) void gemm_qkv(
    const u16* __restrict__ A, const u16* __restrict__ Bt,
    const float* __restrict__ b0, const float* __restrict__ b1,
    const float* __restrict__ b2,
    u16* __restrict__ Qo, u16* __restrict__ Ko, u16* __restrict__ Vto,
    float* __restrict__ Fo)
{
  constexpr int MREP = BM / 32;
  __shared__ u16 As[3][BM * 32];
  __shared__ u16 Bs[3][128 * 32];
  const int tid = threadIdx.x, lane = tid & 63, w = tid >> 6;
  const int fr = lane & 15, fq = lane >> 4;
  const int wr = w >> 1, wc = w & 1;
  const int m0 = blockIdx.x * BM;
  const int n0 = blockIdx.y * 128;
  f32x4 acc[MREP][4] = {};

  auto stage = [&](int buf, int k0) {
#pragma unroll
    for (int i = 0; i < BM / 64; ++i) {     // A: BM rows x 32 (4 chunks/row)
      int b16 = i * 256 + tid;
      int row = b16 >> 2, ch = b16 & 3;
      GLOAD16(A + (size_t)(m0 + row) * DM + k0 + ((ch ^ swz4(row)) * 8), &As[buf][b16 * 8]);
    }
#pragma unroll
    for (int i = 0; i < 2; ++i) {
      int b16 = i * 256 + tid;
      int row = b16 >> 2, ch = b16 & 3;
      GLOAD16(Bt + (size_t)(n0 + row) * DM + k0 + ((ch ^ swz4(row)) * 8), &Bs[buf][b16 * 8]);
    }
  };

  const int NK = DM / 32;   // 32 K-steps
  stage(0, 0);
  stage(1, 32);
  for (int j = 0; j < NK; ++j) {
    if (j + 1 < NK) {
      if constexpr (BM == 128) asm volatile("s_waitcnt vmcnt(4)" ::: "memory");
      else                     asm volatile("s_waitcnt vmcnt(3)" ::: "memory");
    } else {
      asm volatile("s_waitcnt vmcnt(0)" ::: "memory");
    }
    __builtin_amdgcn_s_barrier();
    __builtin_amdgcn_sched_barrier(0);      // keep ds_reads below the barrier

    const u16* Al = As[j % 3];
    const u16* Bl = Bs[j % 3];
    bf16x8 av[MREP], bv[4];
#pragma unroll
    for (int m = 0; m < MREP; ++m) {
      int row = wr * (BM / 2) + m * 16 + fr;
      av[m] = *(const bf16x8*)&Al[row * 32 + ((fq ^ swz4(row)) * 8)];
    }
#pragma unroll
    for (int n = 0; n < 4; ++n) {
      int row = wc * 64 + n * 16 + fr;
      bv[n] = *(const bf16x8*)&Bl[row * 32 + ((fq ^ swz4(row)) * 8)];
    }
    __builtin_amdgcn_s_setprio(1);
#pragma unroll
    for (int m = 0; m < MREP; ++m)
#pragma unroll
      for (int n = 0; n < 4; ++n)
        acc[m][n] = __builtin_amdgcn_mfma_f32_16x16x32_bf16(av[m], bv[n], acc[m][n], 0, 0, 0);
    __builtin_amdgcn_s_setprio(0);

    if (j + 2 < NK) stage((j + 2) % 3, (j + 2) * 32);
  }

  if (MODE == 0) {
    int nloc = n0 & 1023;
    int mat = n0 >> 10;
    const float* bias = (mat == 0) ? b0 : ((mat == 1) ? b1 : b2);
    const float scl = (mat == 0) ? 0.18033688f : 1.0f;   // 0.125*log2(e) in Q
#pragma unroll
    for (int m = 0; m < MREP; ++m) {
      int row = m0 + wr * (BM / 2) + m * 16 + fq * 4;
#pragma unroll
      for (int n = 0; n < 4; ++n) {
        int col = nloc + wc * 64 + n * 16 + fr;
        float bc = bias[col];
        if (mat == 2) {
          u16x4 v4;
#pragma unroll
          for (int r = 0; r < 4; ++r) v4[r] = f2bf(acc[m][n][r] + bc);
          // PV-tile layout write (row..row+3 are 4 consecutive kv tokens)
          int bp   = row >> 11;              // batch
          int tkv  = (row & 2047) >> 6;      // kv tile of 64
          int kvin = row & 63;
          int kb   = kvin >> 4, fqv = (kvin >> 2) & 3;
          int hh   = col >> 6, dh = col & 63;
          int db2  = dh >> 4;
          size_t base = (((size_t)bp * NH + hh) * 32 + tkv) * 4096;
          int off = (db2 * 2 + (kb >> 1)) * 512 + (fqv * 16 + (dh & 15)) * 8 + (kb & 1) * 4;
          *(u16x4*)(Vto + base + off) = v4;
        } else {
          u16* dst = (mat == 0) ? Qo : Ko;
#pragma unroll
          for (int r = 0; r < 4; ++r)
            dst[(size_t)(row + r) * DM + col] = f2bf((acc[m][n][r] + bc) * scl);
        }
      }
    }
  } else {
#pragma unroll
    for (int m = 0; m < MREP; ++m) {
      int row = m0 + wr * (BM / 2) + m * 16 + fq * 4;
#pragma unroll
      for (int n = 0; n < 4; ++n) {
        int col = n0 + wc * 64 + n * 16 + fr;
        float bc = b0[col];
#pragma unroll
        for (int r = 0; r < 4; ++r)
          Fo[(size_t)(row + r) * DM + col] = acc[m][n][r] + bc;
      }
    }
  }
}

// ---------------- flash attention (R26 verbatim: conflict-free V tiles) ----
__global__ __launch_bounds__(256, 4) void attn_kernel(
    const u16* __restrict__ Qg, const u16* __restrict__ Kg,
    const u16* __restrict__ Vt, u16* __restrict__ Og)
{
  __shared__ u16 SM[16384];   // [0,8192) K dbuf 2x[64][64]; [8192,16384) V dbuf
  const int tid = threadIdx.x, lane = tid & 63, w = tid >> 6;
  const int fr = lane & 15, fq = lane >> 4;
  const int bid = blockIdx.x;                // 1024 blocks
  const int bh = bid & 31;                   // 32 (b,h) groups
  const int g = (bid >> 5) & 7;
  const int kq = bid >> 8;                   // 0..3 (the +256 co-residence axis)
  const int qt = (kq == 0) ? (31 - g) : (kq == 1) ? (16 + g)
               : (kq == 2) ? (15 - g) : g;
  const int b = bh >> 4, h = bh & 15;
  const size_t rowbase = (size_t)b * SL;
  const int nt = qt + 1;

  const int qrow = qt * 64 + w * 16 + fr;
  bf16x8 qa[2];
#pragma unroll
  for (int c = 0; c < 2; ++c)
    qa[c] = *(const bf16x8*)(Qg + (rowbase + qrow) * DM + h * 64 + c * 32 + fq * 8);

  s16x4 ones1;
  { union { u16 u[4]; s16x4 s; } t1;
    t1.u[0] = 0x3F80; t1.u[1] = 0x3F80; t1.u[2] = 0x3F80; t1.u[3] = 0x3F80;
    ones1 = t1.s; }

  const size_t vtile0 = (((size_t)b * NH + h) * 32) * 4096;  // + t*4096

  float mrow = -INFINITY;
  f32x4 osum = {};   // ones-A PV accumulator; every lane holds full row sum
  f32x4 o[4] = {};   // O^T frags: q=fr, d = db*16 + fq*4 + r

  auto stage = [&](int buf, int t) {
#pragma unroll
    for (int i = 0; i < 2; ++i) {            // K tile [kv=64][d=64]
      int b16 = i * 256 + tid;
      int row = b16 >> 3, ch = b16 & 7;
      GLOAD16(Kg + (rowbase + t * 64 + row) * DM + h * 64 + ((ch ^ (row & 7)) * 8),
              &SM[buf * 4096 + b16 * 8]);
    }
#pragma unroll
    for (int i = 0; i < 2; ++i) {            // V PV-tile: linear 8KB copy
      int c16 = i * 256 + tid;
      GLOAD16(Vt + vtile0 + (size_t)t * 4096 + c16 * 8,
              &SM[8192 + buf * 4096 + c16 * 8]);
    }
  };

  stage(0, 0);
  __syncthreads();
  int buf = 0;

  for (int t = 0; t < nt; ++t) {
    if (t + 1 < nt) stage(buf ^ 1, t + 1);
    const u16* Kl = &SM[buf * 4096];
    const u16* Vl = &SM[8192 + buf * 4096];

    // QK^T (Q pre-scaled, so st is already in log2-domain units)
    f32x4 st[4];
    __builtin_amdgcn_s_setprio(1);
#pragma unroll
    for (int kb = 0; kb < 4; ++kb) {
      int row = kb * 16 + fr;
      bf16x8 kf0 = *(const bf16x8*)&Kl[row * 64 + ((fq ^ (row & 7)) * 8)];
      bf16x8 kf1 = *(const bf16x8*)&Kl[row * 64 + (((4 + fq) ^ (row & 7)) * 8)];
      f32x4 s0 = {};
      s0 = __builtin_amdgcn_mfma_f32_16x16x32_bf16(kf0, qa[0], s0, 0, 0, 0);
      st[kb] = __builtin_amdgcn_mfma_f32_16x16x32_bf16(kf1, qa[1], s0, 0, 0, 0);
    }
    __builtin_amdgcn_s_setprio(0);

    if (t == qt) {                           // causal mask, diagonal tile only
      const int kvb = t * 64 + fq * 4;
#pragma unroll
      for (int kb = 0; kb < 4; ++kb)
#pragma unroll
        for (int r = 0; r < 4; ++r)
          if (kvb + kb * 16 + r > qrow) st[kb][r] = -INFINITY;
    }

    // row max: max3 chains in-lane, then across the 4 fq lanes of this q
    float pa = max3f(st[0][0], st[0][1], st[0][2]);
    float pb = max3f(st[0][3], st[1][0], st[1][1]);
    float pc = max3f(st[1][2], st[1][3], st[2][0]);
    float pd = max3f(st[2][1], st[2][2], st[2][3]);
    float pe = max3f(st[3][0], st[3][1], st[3][2]);
    float pm = max3f(max3f(pa, pb, pc), max3f(pd, pe, st[3][3]), -INFINITY);
    pm = fmaxf(pm, __shfl_xor(pm, 16, 64));
    pm = fmaxf(pm, __shfl_xor(pm, 32, 64));

    // T13 defer-max: only rescale when the new tile max grows by > 8
    if (__any(pm > mrow + 8.f)) {
      float nm = fmaxf(mrow, pm);
      float alpha = fexp2(mrow - nm);
      mrow = nm;
#pragma unroll
      for (int r = 0; r < 4; ++r) osum[r] *= alpha;
#pragma unroll
      for (int db = 0; db < 4; ++db)
#pragma unroll
        for (int r = 0; r < 4; ++r) o[db][r] *= alpha;
    }

    // exp + pack; P stays in D-layout == PV B-layout
    unsigned pk2[4][2];
#pragma unroll
    for (int kb = 0; kb < 4; ++kb) {
      float p0 = fexp2(st[kb][0] - mrow);
      float p1 = fexp2(st[kb][1] - mrow);
      float p2 = fexp2(st[kb][2] - mrow);
      float p3 = fexp2(st[kb][3] - mrow);
      pk2[kb][0] = cvtpk(p0, p1);
      pk2[kb][1] = cvtpk(p2, p3);
    }

    // PV: dense b128 V reads (conflict-free), kb pair per read
    __builtin_amdgcn_s_setprio(1);
#pragma unroll
    for (int j = 0; j < 2; ++j) {
      union { unsigned u[2]; s16x4 s; } bb0, bb1;
      bb0.u[0] = pk2[2 * j][0];     bb0.u[1] = pk2[2 * j][1];
      bb1.u[0] = pk2[2 * j + 1][0]; bb1.u[1] = pk2[2 * j + 1][1];
      osum = pv_mfma(ones1, bb0.s, osum);
      osum = pv_mfma(ones1, bb1.s, osum);
#pragma unroll
      for (int db = 0; db < 4; ++db) {
        union { bf16x8 v; s16x4 s2[2]; } vv;
        vv.v = *(const bf16x8*)&Vl[(db * 2 + j) * 512 + lane * 8];
        o[db] = pv_mfma(vv.s2[0], bb0.s, o[db]);
        o[db] = pv_mfma(vv.s2[1], bb1.s, o[db]);
      }
    }
    __builtin_amdgcn_s_setprio(0);

    __syncthreads();
    buf ^= 1;
  }

  // epilogue: osum[0] already holds the full l for this q-row in every lane
  float inv = 1.0f / osum[0];

  u16* Tb = &SM[w * 1152];   // per-wave [16][72]
#pragma unroll
  for (int db = 0; db < 4; ++db)
#pragma unroll
    for (int w2 = 0; w2 < 2; ++w2) {
      unsigned pk = cvtpk(o[db][2 * w2] * inv, o[db][2 * w2 + 1] * inv);
      *(unsigned*)&Tb[fr * 72 + db * 16 + fq * 4 + 2 * w2] = pk;
    }
  int rr = lane >> 2, cc = (lane & 3) * 16;
  size_t gbase = (rowbase + qt * 64 + w * 16 + rr) * DM + h * 64 + cc;
#pragma unroll
  for (int j2 = 0; j2 < 2; ++j2)
    *(u16x8*)(Og + gbase + j2 * 8) = *(const u16x8*)&Tb[rr * 72 + cc + j2 * 8];
}

// ---------------- launch ----------------
extern "C" void kernel_launch(void* const* d_in, const int* in_sizes, int n_in,
                              void* d_out, int out_size, void* d_ws, size_t ws_size,
                              hipStream_t stream) {
  const float* x  = (const float*)d_in[0];
  const float* wq = (const float*)d_in[1];
  const float* bq = (const float*)d_in[2];
  const float* wk = (const float*)d_in[3];
  const float* bk = (const float*)d_in[4];
  const float* wv = (const float*)d_in[5];
  const float* bv = (const float*)d_in[6];
  const float* wo = (const float*)d_in[7];
  const float* bo = (const float*)d_in[8];

  char* ws = (char*)d_ws;
  u16* Xb   = (u16*)ws;                          // 8 MB  bf16 X; reused as attn output
  u16* Wall = (u16*)(ws + 8u  * 1024 * 1024);    // 8 MB  Wq/Wk/Wv/Wo ^T stacked
  u16* Qb   = (u16*)(ws + 16u * 1024 * 1024);    // 8 MB
  u16* Kb   = (u16*)(ws + 24u * 1024 * 1024);    // 8 MB
  u16* VtG  = (u16*)(ws + 32u * 1024 * 1024);    // 8 MB  V PV-tiles [b][h][t][4096]

  hipLaunchKernelGGL(prep, dim3(1024 + 2048), dim3(256), 0, stream,
                     x, wq, wk, wv, wo, Xb, Wall);

  hipLaunchKernelGGL((gemm_qkv<0, 128>), dim3(TOK / 128, 3072 / 128), dim3(256), 0, stream,
                     Xb, Wall, bq, bk, bv, Qb, Kb, VtG, (float*)nullptr);

  hipLaunchKernelGGL(attn_kernel, dim3(32 * BB * NH), dim3(256), 0, stream,
                     Qb, Kb, VtG, Xb);

  hipLaunchKernelGGL((gemm_qkv<1, 64>), dim3(TOK / 64, DM / 128), dim3(256), 0, stream,
                     Xb, Wall + 3u * (1u << 20), bo, (const float*)nullptr, (const float*)nullptr,
                     (u16*)nullptr, (u16*)nullptr, (u16*)nullptr, (float*)d_out);
}

// Round 28
// 95.060 us; speedup vs baseline: 1.0059x; 1.0059x over previous
//
#include <hip/hip_runtime.h>
#include <hip/hip_bf16.h>
#include <math.h>

typedef unsigned short u16;
typedef __bf16 bf16x8 __attribute__((ext_vector_type(8)));
typedef short s16x4 __attribute__((ext_vector_type(4)));
typedef float f32x4 __attribute__((ext_vector_type(4)));
typedef u16 u16x8 __attribute__((ext_vector_type(8)));
typedef u16 u16x4 __attribute__((ext_vector_type(4)));

#define DM 1024
#define NH 16
#define SL 2048
#define BB 2
#define TOK (BB * SL)   // 4096 tokens

__device__ __forceinline__ u16 f2bf(float f) {
  union { float f; unsigned u; } v; v.f = f;
  unsigned r = v.u + 0x7FFFu + ((v.u >> 16) & 1u);
  return (u16)(r >> 16);
}

__device__ __forceinline__ float fexp2(float x) {
  float r; asm("v_exp_f32 %0, %1" : "=v"(r) : "v"(x)); return r;
}

__device__ __forceinline__ unsigned cvtpk(float lo, float hi) {
  unsigned r;
  asm("v_cvt_pk_bf16_f32 %0, %1, %2" : "=v"(r) : "v"(lo), "v"(hi));
  return r;
}

__device__ __forceinline__ float max3f(float a, float b, float c) {
  return fmaxf(fmaxf(a, b), c);   // clang fuses to v_max3_f32
}

// K=16 MFMA: A frag s16x4 = A[row=lane&15][k=(lane>>4)*4 + 0..3].
__device__ __forceinline__ f32x4 pv_mfma(s16x4 a, s16x4 b, f32x4 c) {
#if __has_builtin(__builtin_amdgcn_mfma_f32_16x16x16bf16_1k)
  return __builtin_amdgcn_mfma_f32_16x16x16bf16_1k(a, b, c, 0, 0, 0);
#else
  asm("v_mfma_f32_16x16x16_bf16 %0, %1, %2, %0" : "+v"(c) : "v"(a), "v"(b));
  return c;
#endif
}

typedef __attribute__((address_space(1))) const unsigned GU;
typedef __attribute__((address_space(3))) unsigned LU;
#define GLOAD16(g, l) __builtin_amdgcn_global_load_lds((GU*)(g), (LU*)(l), 16, 0, 0)

// ---------------- prep: 4x weight transpose-cast + x cast, one launch ------
__global__ __launch_bounds__(256) void prep(
    const float* __restrict__ x,
    const float* __restrict__ w0, const float* __restrict__ w1,
    const float* __restrict__ w2, const float* __restrict__ w3,
    u16* __restrict__ Xb, u16* __restrict__ Wall) {
  __shared__ u16 T[64][72];
  int bid = blockIdx.x;
  int tid = threadIdx.x;
  if (bid < 1024) {            // transpose: mat = bid>>8, 16x16 tiles of 64
    int mat = bid >> 8;
    const float* in = (mat == 0) ? w0 : (mat == 1) ? w1 : (mat == 2) ? w2 : w3;
    u16* o = Wall + ((size_t)mat << 20);
    int t2 = bid & 255;
    int k0 = (t2 & 15) * 64, n0 = (t2 >> 4) * 64;
    int r = tid >> 2;
    int c0 = (tid & 3) * 16;
#pragma unroll
    for (int j = 0; j < 16; j += 4) {
      float4 f = *(const float4*)(in + (size_t)(k0 + r) * 1024 + n0 + c0 + j);
      T[c0 + j + 0][r] = f2bf(f.x);
      T[c0 + j + 1][r] = f2bf(f.y);
      T[c0 + j + 2][r] = f2bf(f.z);
      T[c0 + j + 3][r] = f2bf(f.w);
    }
    __syncthreads();
    int n = tid >> 2, k1 = (tid & 3) * 16;
#pragma unroll
    for (int j = 0; j < 16; j += 8)
      *(u16x8*)(o + (size_t)(n0 + n) * 1024 + k0 + k1 + j) = *(const u16x8*)&T[n][k1 + j];
  } else {                     // cast x -> bf16 (2048 blocks x 256 x 8)
    int i = ((bid - 1024) * 256 + tid) * 8;
    float4 a = *(const float4*)(x + i);
    float4 b = *(const float4*)(x + i + 4);
    u16x8 o;
    o[0]=f2bf(a.x); o[1]=f2bf(a.y); o[2]=f2bf(a.z); o[3]=f2bf(a.w);
    o[4]=f2bf(b.x); o[5]=f2bf(b.y); o[6]=f2bf(b.z); o[7]=f2bf(b.w);
    *(u16x8*)(Xb + i) = o;
  }
}

// ---------------- GEMM: 3-buffer ring, BK=32, BM templated ----------------
// Loads per stage = BM/64 (A) + 2 (B). Counted-vmcnt steady-state wait must
// equal loads-per-stage: BM=128 -> vmcnt(4); BM=64 -> vmcnt(3).
template<int MODE, int BM>
__global__ __launch_bounds__(256) void gemm_qkv(
    const u16* __restrict__ A, const u16* __restrict__ Bt,
    const float* __restrict__ b0, const float* __restrict__ b1,
    const float* __restrict__ b2,
    u16* __restrict__ Qo, u16* __restrict__ Ko, u16* __restrict__ Vto,
    float* __restrict__ Fo)
{
  constexpr int MREP = BM / 32;
  __shared__ u16 As[3][BM * 32];
  __shared__ u16 Bs[3][128 * 32];
  const int tid = threadIdx.x, lane = tid & 63, w = tid >> 6;
  const int fr = lane & 15, fq = lane >> 4;
  const int wr = w >> 1, wc = w & 1;
  const int m0 = blockIdx.x * BM;
  const int n0 = blockIdx.y * 128;
  f32x4 acc[MREP][4] = {};

  auto stage = [&](int buf, int k0) {
#pragma unroll
    for (int i = 0; i < BM / 64; ++i) {     // A: BM rows x 32 (4 chunks/row)
      int b16 = i * 256 + tid;
      int row = b16 >> 2, ch = b16 & 3;
      GLOAD16(A + (size_t)(m0 + row) * DM + k0 + ((ch ^ (row & 3)) * 8), &As[buf][b16 * 8]);
    }
#pragma unroll
    for (int i = 0; i < 2; ++i) {
      int b16 = i * 256 + tid;
      int row = b16 >> 2, ch = b16 & 3;
      GLOAD16(Bt + (size_t)(n0 + row) * DM + k0 + ((ch ^ (row & 3)) * 8), &Bs[buf][b16 * 8]);
    }
  };

  const int NK = DM / 32;   // 32 K-steps
  stage(0, 0);
  stage(1, 32);
  for (int j = 0; j < NK; ++j) {
    if (j + 1 < NK) {
      if constexpr (BM == 128) asm volatile("s_waitcnt vmcnt(4)" ::: "memory");
      else                     asm volatile("s_waitcnt vmcnt(3)" ::: "memory");
    } else {
      asm volatile("s_waitcnt vmcnt(0)" ::: "memory");
    }
    __builtin_amdgcn_s_barrier();
    __builtin_amdgcn_sched_barrier(0);      // keep ds_reads below the barrier

    const u16* Al = As[j % 3];
    const u16* Bl = Bs[j % 3];
    bf16x8 av[MREP], bv[4];
#pragma unroll
    for (int m = 0; m < MREP; ++m) {
      int row = wr * (BM / 2) + m * 16 + fr;
      av[m] = *(const bf16x8*)&Al[row * 32 + ((fq ^ (row & 3)) * 8)];
    }
#pragma unroll
    for (int n = 0; n < 4; ++n) {
      int row = wc * 64 + n * 16 + fr;
      bv[n] = *(const bf16x8*)&Bl[row * 32 + ((fq ^ (row & 3)) * 8)];
    }
    __builtin_amdgcn_s_setprio(1);
#pragma unroll
    for (int m = 0; m < MREP; ++m)
#pragma unroll
      for (int n = 0; n < 4; ++n)
        acc[m][n] = __builtin_amdgcn_mfma_f32_16x16x32_bf16(av[m], bv[n], acc[m][n], 0, 0, 0);
    __builtin_amdgcn_s_setprio(0);

    if (j + 2 < NK) stage((j + 2) % 3, (j + 2) * 32);
  }

  if (MODE == 0) {
    int nloc = n0 & 1023;
    int mat = n0 >> 10;
    const float* bias = (mat == 0) ? b0 : ((mat == 1) ? b1 : b2);
    const float scl = (mat == 0) ? 0.18033688f : 1.0f;   // 0.125*log2(e) in Q
#pragma unroll
    for (int m = 0; m < MREP; ++m) {
      int row = m0 + wr * (BM / 2) + m * 16 + fq * 4;
#pragma unroll
      for (int n = 0; n < 4; ++n) {
        int col = nloc + wc * 64 + n * 16 + fr;
        float bc = bias[col];
        if (mat == 2) {
          u16x4 v4;
#pragma unroll
          for (int r = 0; r < 4; ++r) v4[r] = f2bf(acc[m][n][r] + bc);
          // PV-tile layout write (row..row+3 are 4 consecutive kv tokens)
          int bp   = row >> 11;              // batch
          int tkv  = (row & 2047) >> 6;      // kv tile of 64
          int kvin = row & 63;
          int kb   = kvin >> 4, fqv = (kvin >> 2) & 3;
          int hh   = col >> 6, dh = col & 63;
          int db2  = dh >> 4;
          size_t base = (((size_t)bp * NH + hh) * 32 + tkv) * 4096;
          int off = (db2 * 2 + (kb >> 1)) * 512 + (fqv * 16 + (dh & 15)) * 8 + (kb & 1) * 4;
          *(u16x4*)(Vto + base + off) = v4;
        } else {
          u16* dst = (mat == 0) ? Qo : Ko;
#pragma unroll
          for (int r = 0; r < 4; ++r)
            dst[(size_t)(row + r) * DM + col] = f2bf((acc[m][n][r] + bc) * scl);
        }
      }
    }
  } else {
#pragma unroll
    for (int m = 0; m < MREP; ++m) {
      int row = m0 + wr * (BM / 2) + m * 16 + fq * 4;
#pragma unroll
      for (int n = 0; n < 4; ++n) {
        int col = n0 + wc * 64 + n * 16 + fr;
        float bc = b0[col];
#pragma unroll
        for (int r = 0; r < 4; ++r)
          Fo[(size_t)(row + r) * DM + col] = acc[m][n][r] + bc;
      }
    }
  }
}

// ---------------- flash attention (best measured: conflict-free V tiles) ---
// Sum-balanced qt mapping: co-resident blocks {bid+256k} share bh (KV panel
// in L2) and get qt {31-g, 16+g, 15-g, g} (sum 62 for every g).
// V in per-(b,h,t) 8KB PV-tiles: linear stage, dense ds_read_b128 reads.
__global__ __launch_bounds__(256, 4) void attn_kernel(
    const u16* __restrict__ Qg, const u16* __restrict__ Kg,
    const u16* __restrict__ Vt, u16* __restrict__ Og)
{
  __shared__ u16 SM[16384];   // [0,8192) K dbuf 2x[64][64]; [8192,16384) V dbuf
  const int tid = threadIdx.x, lane = tid & 63, w = tid >> 6;
  const int fr = lane & 15, fq = lane >> 4;
  const int bid = blockIdx.x;                // 1024 blocks
  const int bh = bid & 31;                   // 32 (b,h) groups
  const int g = (bid >> 5) & 7;
  const int kq = bid >> 8;                   // 0..3 (the +256 co-residence axis)
  const int qt = (kq == 0) ? (31 - g) : (kq == 1) ? (16 + g)
               : (kq == 2) ? (15 - g) : g;
  const int b = bh >> 4, h = bh & 15;
  const size_t rowbase = (size_t)b * SL;
  const int nt = qt + 1;

  const int qrow = qt * 64 + w * 16 + fr;
  bf16x8 qa[2];
#pragma unroll
  for (int c = 0; c < 2; ++c)
    qa[c] = *(const bf16x8*)(Qg + (rowbase + qrow) * DM + h * 64 + c * 32 + fq * 8);

  s16x4 ones1;
  { union { u16 u[4]; s16x4 s; } t1;
    t1.u[0] = 0x3F80; t1.u[1] = 0x3F80; t1.u[2] = 0x3F80; t1.u[3] = 0x3F80;
    ones1 = t1.s; }

  const size_t vtile0 = (((size_t)b * NH + h) * 32) * 4096;  // + t*4096

  float mrow = -INFINITY;
  f32x4 osum = {};   // ones-A PV accumulator; every lane holds full row sum
  f32x4 o[4] = {};   // O^T frags: q=fr, d = db*16 + fq*4 + r

  auto stage = [&](int buf, int t) {
#pragma unroll
    for (int i = 0; i < 2; ++i) {            // K tile [kv=64][d=64]
      int b16 = i * 256 + tid;
      int row = b16 >> 3, ch = b16 & 7;
      GLOAD16(Kg + (rowbase + t * 64 + row) * DM + h * 64 + ((ch ^ (row & 7)) * 8),
              &SM[buf * 4096 + b16 * 8]);
    }
#pragma unroll
    for (int i = 0; i < 2; ++i) {            // V PV-tile: linear 8KB copy
      int c16 = i * 256 + tid;
      GLOAD16(Vt + vtile0 + (size_t)t * 4096 + c16 * 8,
              &SM[8192 + buf * 4096 + c16 * 8]);
    }
  };

  stage(0, 0);
  __syncthreads();
  int buf = 0;

  for (int t = 0; t < nt; ++t) {
    if (t + 1 < nt) stage(buf ^ 1, t + 1);
    const u16* Kl = &SM[buf * 4096];
    const u16* Vl = &SM[8192 + buf * 4096];

    // QK^T (Q pre-scaled, so st is already in log2-domain units)
    f32x4 st[4];
    __builtin_amdgcn_s_setprio(1);
#pragma unroll
    for (int kb = 0; kb < 4; ++kb) {
      int row = kb * 16 + fr;
      bf16x8 kf0 = *(const bf16x8*)&Kl[row * 64 + ((fq ^ (row & 7)) * 8)];
      bf16x8 kf1 = *(const bf16x8*)&Kl[row * 64 + (((4 + fq) ^ (row & 7)) * 8)];
      f32x4 s0 = {};
      s0 = __builtin_amdgcn_mfma_f32_16x16x32_bf16(kf0, qa[0], s0, 0, 0, 0);
      st[kb] = __builtin_amdgcn_mfma_f32_16x16x32_bf16(kf1, qa[1], s0, 0, 0, 0);
    }
    __builtin_amdgcn_s_setprio(0);

    if (t == qt) {                           // causal mask, diagonal tile only
      const int kvb = t * 64 + fq * 4;
#pragma unroll
      for (int kb = 0; kb < 4; ++kb)
#pragma unroll
        for (int r = 0; r < 4; ++r)
          if (kvb + kb * 16 + r > qrow) st[kb][r] = -INFINITY;
    }

    // row max: max3 chains in-lane, then across the 4 fq lanes of this q
    float pa = max3f(st[0][0], st[0][1], st[0][2]);
    float pb = max3f(st[0][3], st[1][0], st[1][1]);
    float pc = max3f(st[1][2], st[1][3], st[2][0]);
    float pd = max3f(st[2][1], st[2][2], st[2][3]);
    float pe = max3f(st[3][0], st[3][1], st[3][2]);
    float pm = max3f(max3f(pa, pb, pc), max3f(pd, pe, st[3][3]), -INFINITY);
    pm = fmaxf(pm, __shfl_xor(pm, 16, 64));
    pm = fmaxf(pm, __shfl_xor(pm, 32, 64));

    // T13 defer-max: only rescale when the new tile max grows by > 8
    if (__any(pm > mrow + 8.f)) {
      float nm = fmaxf(mrow, pm);
      float alpha = fexp2(mrow - nm);
      mrow = nm;
#pragma unroll
      for (int r = 0; r < 4; ++r) osum[r] *= alpha;
#pragma unroll
      for (int db = 0; db < 4; ++db)
#pragma unroll
        for (int r = 0; r < 4; ++r) o[db][r] *= alpha;
    }

    // exp + pack; P stays in D-layout == PV B-layout
    unsigned pk2[4][2];
#pragma unroll
    for (int kb = 0; kb < 4; ++kb) {
      float p0 = fexp2(st[kb][0] - mrow);
      float p1 = fexp2(st[kb][1] - mrow);
      float p2 = fexp2(st[kb][2] - mrow);
      float p3 = fexp2(st[kb][3] - mrow);
      pk2[kb][0] = cvtpk(p0, p1);
      pk2[kb][1] = cvtpk(p2, p3);
    }

    // PV: dense b128 V reads (conflict-free), kb pair per read
    __builtin_amdgcn_s_setprio(1);
#pragma unroll
    for (int j = 0; j < 2; ++j) {
      union { unsigned u[2]; s16x4 s; } bb0, bb1;
      bb0.u[0] = pk2[2 * j][0];     bb0.u[1] = pk2[2 * j][1];
      bb1.u[0] = pk2[2 * j + 1][0]; bb1.u[1] = pk2[2 * j + 1][1];
      osum = pv_mfma(ones1, bb0.s, osum);
      osum = pv_mfma(ones1, bb1.s, osum);
#pragma unroll
      for (int db = 0; db < 4; ++db) {
        union { bf16x8 v; s16x4 s2[2]; } vv;
        vv.v = *(const bf16x8*)&Vl[(db * 2 + j) * 512 + lane * 8];
        o[db] = pv_mfma(vv.s2[0], bb0.s, o[db]);
        o[db] = pv_mfma(vv.s2[1], bb1.s, o[db]);
      }
    }
    __builtin_amdgcn_s_setprio(0);

    __syncthreads();
    buf ^= 1;
  }

  // epilogue: osum[0] already holds the full l for this q-row in every lane
  float inv = 1.0f / osum[0];

  u16* Tb = &SM[w * 1152];   // per-wave [16][72]
#pragma unroll
  for (int db = 0; db < 4; ++db)
#pragma unroll
    for (int w2 = 0; w2 < 2; ++w2) {
      unsigned pk = cvtpk(o[db][2 * w2] * inv, o[db][2 * w2 + 1] * inv);
      *(unsigned*)&Tb[fr * 72 + db * 16 + fq * 4 + 2 * w2] = pk;
    }
  int rr = lane >> 2, cc = (lane & 3) * 16;
  size_t gbase = (rowbase + qt * 64 + w * 16 + rr) * DM + h * 64 + cc;
#pragma unroll
  for (int j2 = 0; j2 < 2; ++j2)
    *(u16x8*)(Og + gbase + j2 * 8) = *(const u16x8*)&Tb[rr * 72 + cc + j2 * 8];
}

// ---------------- launch ----------------
extern "C" void kernel_launch(void* const* d_in, const int* in_sizes, int n_in,
                              void* d_out, int out_size, void* d_ws, size_t ws_size,
                              hipStream_t stream) {
  const float* x  = (const float*)d_in[0];
  const float* wq = (const float*)d_in[1];
  const float* bq = (const float*)d_in[2];
  const float* wk = (const float*)d_in[3];
  const float* bk = (const float*)d_in[4];
  const float* wv = (const float*)d_in[5];
  const float* bv = (const float*)d_in[6];
  const float* wo = (const float*)d_in[7];
  const float* bo = (const float*)d_in[8];

  char* ws = (char*)d_ws;
  u16* Xb   = (u16*)ws;                          // 8 MB  bf16 X; reused as attn output
  u16* Wall = (u16*)(ws + 8u  * 1024 * 1024);    // 8 MB  Wq/Wk/Wv/Wo ^T stacked
  u16* Qb   = (u16*)(ws + 16u * 1024 * 1024);    // 8 MB
  u16* Kb   = (u16*)(ws + 24u * 1024 * 1024);    // 8 MB
  u16* VtG  = (u16*)(ws + 32u * 1024 * 1024);    // 8 MB  V PV-tiles [b][h][t][4096]

  hipLaunchKernelGGL(prep, dim3(1024 + 2048), dim3(256), 0, stream,
                     x, wq, wk, wv, wo, Xb, Wall);

  hipLaunchKernelGGL((gemm_qkv<0, 128>), dim3(TOK / 128, 3072 / 128), dim3(256), 0, stream,
                     Xb, Wall, bq, bk, bv, Qb, Kb, VtG, (float*)nullptr);

  hipLaunchKernelGGL(attn_kernel, dim3(32 * BB * NH), dim3(256), 0, stream,
                     Qb, Kb, VtG, Xb);

  hipLaunchKernelGGL((gemm_qkv<1, 64>), dim3(TOK / 64, DM / 128), dim3(256), 0, stream,
                     Xb, Wall + 3u * (1u << 20), bo, (const float*)nullptr, (const float*)nullptr,
                     (u16*)nullptr, (u16*)nullptr, (u16*)nullptr, (float*)d_out);
}